// Round 4
// baseline (127.035 us; speedup 1.0000x reference)
//
#include <hip/hip_runtime.h>
#include <hip/hip_bf16.h>

// Problem constants (B,H,W,C) = (4,56,56,256), nh=8, K=7, lr=4, hd=32
#define BD 4
#define HD_ 56
#define WD 56
#define CD 256
#define NH 8
#define KW 7
#define LR 4
#define HDIM 32
#define MB (HD_*WD)              // 3136 rows per batch
#define NROWS (BD*MB)            // 12544 total rows
#define QK_PER_B (HD_*WD*32)     // 100352  (q/k per-batch elements)
#define V_PER_B  (HD_*WD*256)    // 802816

typedef short short8 __attribute__((ext_vector_type(8)));   // 8 bf16 (4 VGPRs)
typedef float floatx4 __attribute__((ext_vector_type(4)));  // MFMA C/D

static __device__ inline ushort f2bf(float f) {
    __hip_bfloat16 h = __float2bfloat16(f);
    return *(ushort*)&h;
}
static __device__ inline float bf2f(uint h16) {          // h16 = bf16 in low 16 bits
    union { uint u; float f; } c; c.u = h16 << 16; return c.f;
}
static __device__ inline float bf2f_hi(uint u) {         // bf16 in high 16 bits
    union { uint v; float f; } c; c.v = u & 0xffff0000u; return c.f;
}

// global -> LDS async DMA, 16B per lane. LDS dest is wave-uniform base +
// lane*16 (HW behavior); global src is per-lane.
typedef const __attribute__((address_space(1))) void* gp1_t;
typedef __attribute__((address_space(3))) void* sp3_t;
static __device__ __forceinline__ void glds16(const void* g, void* s) {
    __builtin_amdgcn_global_load_lds((gp1_t)g, (sp3_t)s, 16, 0, 0);
}

// ---------------- prep: x->bf16 + transposed bf16 weights + packed bias -----
__global__ __launch_bounds__(256) void prep_all(
    const float* __restrict__ x,
    const float* __restrict__ Wq, const float* __restrict__ Wk,
    const float* __restrict__ Wv, const float* __restrict__ bq,
    const float* __restrict__ bk, const float* __restrict__ bv,
    const float* __restrict__ Wp,
    ushort* __restrict__ xb, ushort* __restrict__ WpkT,
    ushort* __restrict__ WpT, float* __restrict__ pb)
{
    int idx = blockIdx.x * 256 + threadIdx.x;
    if (idx < 401408) {
        float4 f0 = *(const float4*)&x[idx * 8];
        float4 f1 = *(const float4*)&x[idx * 8 + 4];
        union { ushort h[8]; uint4 u; } p;
        p.h[0] = f2bf(f0.x); p.h[1] = f2bf(f0.y); p.h[2] = f2bf(f0.z); p.h[3] = f2bf(f0.w);
        p.h[4] = f2bf(f1.x); p.h[5] = f2bf(f1.y); p.h[6] = f2bf(f1.z); p.h[7] = f2bf(f1.w);
        *(uint4*)&xb[idx * 8] = p.u;
    } else if (idx < 401408 + 81920) {
        int j = idx - 401408;
        int n = j >> 8, k = j & 255;
        float v;
        if (n < 32)       v = Wq[k * 32 + n];
        else if (n < 64)  v = Wk[k * 32 + (n - 32)];
        else              v = Wv[k * 256 + (n - 64)];
        WpkT[j] = f2bf(v);
    } else if (idx < 401408 + 81920 + 65536) {
        int j = idx - (401408 + 81920);
        int n = j >> 8, k = j & 255;
        WpT[j] = f2bf(Wp[k * 256 + n]);
    } else if (idx < 401408 + 81920 + 65536 + 320) {
        int n = idx - (401408 + 81920 + 65536);
        pb[n] = (n < 32) ? bq[n] : (n < 64) ? bk[n - 32] : bv[n - 64];
    }
}

// ---------------- MFMA GEMM: QKV projection (unchanged, proven) -------------
static __device__ __forceinline__ void gemm_core_128x64(
    const ushort* __restrict__ Ag, const ushort* __restrict__ Bg,
    ushort* As, ushort* Bs, int m0, int n0, int t, floatx4 (&acc)[4][2])
{
    const int lane = t & 63, w = t >> 6;
    const int lx = lane & 7, ly = lane >> 3;
    const int koff = (lx ^ ly) << 3;
    const int col = lane & 15, quad = lane >> 4;
    const int swz = (col & 7) << 4;
    const int wm = w >> 1, wn = w & 1;
    char* Ac = (char*)As;
    char* Bc = (char*)Bs;

    for (int k0 = 0; k0 < 256; k0 += 64) {
        __syncthreads();
#pragma unroll
        for (int l = 0; l < 4; ++l) {
            int c = (w << 2) + l;
            int row = (c << 3) + ly;
            glds16(&Ag[(m0 + row) * 256 + k0 + koff], &As[c << 9]);
        }
#pragma unroll
        for (int l = 0; l < 2; ++l) {
            int c = (w << 1) + l;
            int row = (c << 3) + ly;
            glds16(&Bg[(n0 + row) * 256 + k0 + koff], &Bs[c << 9]);
        }
        __syncthreads();
#pragma unroll
        for (int kk = 0; kk < 2; ++kk) {
            const int kx = ((kk << 6) + (quad << 4)) ^ swz;
            short8 b0 = *(short8*)(Bc + ((wn << 5) + col) * 128 + kx);
            short8 b1 = *(short8*)(Bc + ((wn << 5) + 16 + col) * 128 + kx);
#pragma unroll
            for (int mt = 0; mt < 4; ++mt) {
                short8 a = *(short8*)(Ac + ((wm << 6) + (mt << 4) + col) * 128 + kx);
                acc[mt][0] = __builtin_amdgcn_mfma_f32_16x16x32_bf16(a, b0, acc[mt][0], 0, 0, 0);
                acc[mt][1] = __builtin_amdgcn_mfma_f32_16x16x32_bf16(a, b1, acc[mt][1], 0, 0, 0);
            }
        }
    }
}

__global__ __launch_bounds__(256) void mfma_qkv(
    const ushort* __restrict__ xb, const ushort* __restrict__ Bt,
    const float* __restrict__ pb, ushort* __restrict__ Qb,
    ushort* __restrict__ Kb, ushort* __restrict__ Vb)
{
    __shared__ ushort As[128 * 64];
    __shared__ ushort Bs[64 * 64];
    const int t = threadIdx.x;
    const int m0 = blockIdx.y * 128, n0 = blockIdx.x * 64;

    floatx4 acc[4][2] = {};
    gemm_core_128x64(xb, Bt, As, Bs, m0, n0, t, acc);

    const int lane = t & 63, w = t >> 6;
    const int col = lane & 15, quad = lane >> 4;
    const int wm = w >> 1, wn = w & 1;
#pragma unroll
    for (int mt = 0; mt < 4; ++mt) {
#pragma unroll
        for (int nt = 0; nt < 2; ++nt) {
            int gn = n0 + (wn << 5) + (nt << 4) + col;
            float bias = pb[gn];
#pragma unroll
            for (int rg = 0; rg < 4; ++rg) {
                int m = m0 + (wm << 6) + (mt << 4) + (quad << 2) + rg;
                ushort h = f2bf(acc[mt][nt][rg] + bias);
                if (gn < 32)        Qb[m * 32 + gn] = h;
                else if (gn < 64)   Kb[m * 32 + (gn - 32)] = h;
                else                Vb[m * 256 + (gn - 64)] = h;
            }
        }
    }
}

// ---------------- FUSED: NATTEN attention (8 heads) + output projection -----
// Block = (tj, ti, b): one 8x8 query tile, ALL 8 heads sequentially, then the
// 64x256 @ 256x256 out-projection GEMM from LDS. Eliminates the Ab global
// roundtrip (50 MB) and one launch. P zero-holes are head-independent
// (window geometry only) -> zeroed once; Vt K-pad zeroed once.
__global__ __launch_bounds__(256) void natten_fused(
    const ushort* __restrict__ Qb, const ushort* __restrict__ Kb,
    const ushort* __restrict__ Vb, const float* __restrict__ rpb,
    const ushort* __restrict__ WpT, const float* __restrict__ bp,
    float* __restrict__ out)
{
    __shared__ __align__(16) ushort Olds[64 * 264];   // 33792 B
    __shared__ __align__(16) ushort Vt[32 * 232];     // 14848 B
    __shared__ __align__(16) char   Preg[33792];      // P | Ksf | Rs | invS  (GEMM: Bsg)
    ushort* Pl   = (ushort*)Preg;                     // [64][232] bf16, 29696 B
    float4* Ksf  = (float4*)(Preg + 29696);           // 196 x 16 B
    float*  Rs   = (float*)(Preg + 32832);            // 169 x 4 B
    float*  invS = (float*)(Preg + 33512);            // 64 x 4 B (outside Bsg's 32768)
    ushort* Bsg  = (ushort*)Preg;                     // GEMM phase: [256][64] swizzled

    const int tj = blockIdx.x, ti = blockIdx.y, b = blockIdx.z;
    const int t = threadIdx.x;
    const int i0 = ti * 8, j0 = tj * 8;
    const int rs = min(max(i0 - 3, 0), HD_ - 14);
    const int cs = min(max(j0 - 3, 0), WD - 14);

    const int q  = t >> 2, p = t & 3;
    const int qi = q >> 3, qj = q & 7;
    const int i = i0 + qi, j = j0 + qj;
    const int lane = t & 63, w = t >> 6;
    const int col = lane & 15, quad = lane >> 4;

    const int sh = min(max(i - 3, 0), HD_ - KW);
    const int sw = min(max(j - 3, 0), WD - KW);
    const int oh = sh - rs, ow = sw - cs;
    const int rb0 = (sh - i + 6) * 13 + (sw - j + 6);
    const float scale = 0.17677669529663687f;

    // ---- zero P (holes + K-pad) and Vt (K-pad), once
#pragma unroll
    for (int it = 0; it < 8; ++it) {
        int idx = t + (it << 8);
        if (idx < 1856) *(uint4*)&Preg[idx << 4] = make_uint4(0, 0, 0, 0);
    }
#pragma unroll
    for (int it = 0; it < 4; ++it) {
        int idx = t + (it << 8);
        if (idx < 928) *(uint4*)&Vt[idx << 3] = make_uint4(0, 0, 0, 0);
    }

    // ---- prefetch head 0 into regs
    uint4 vreg[4];
    uint2 kreg = make_uint2(0u, 0u), qcur, qnext;
    float rreg = 0.f;
    {
        const ushort* vb = Vb + (size_t)b * V_PER_B;
        const ushort* kb = Kb + (size_t)b * QK_PER_B;
#pragma unroll
        for (int it = 0; it < 4; ++it) {
            int idx = t + it * 256;
            if (idx < 784) {
                int pos = idx >> 2, oct = idx & 3;
                int r = pos / 14, c = pos % 14;
                vreg[it] = *(const uint4*)&vb[(rs + r) * (WD * HDIM) + (cs + c) * HDIM + oct * 8];
            }
        }
        if (t < 196) {
            int r = t / 14, c = t % 14;
            kreg = *(const uint2*)&kb[(rs + r) * (WD * LR) + (cs + c) * LR];
        }
        if (t < 169) rreg = rpb[t];
        qcur = *(const uint2*)&Qb[(size_t)b * QK_PER_B + i * (WD * LR) + j * LR];
    }
    __syncthreads();

    for (int h = 0; h < 8; ++h) {
        // ---- scatter staged regs into LDS
#pragma unroll
        for (int it = 0; it < 4; ++it) {
            int idx = t + it * 256;
            if (idx < 784) {
                int pos = idx >> 2, oct = idx & 3;
                ushort* cp = &Vt[(oct * 8) * 232 + pos];
                union { uint4 u; ushort hh[8]; } vv; vv.u = vreg[it];
#pragma unroll
                for (int e = 0; e < 8; ++e) cp[e * 232] = vv.hh[e];
            }
        }
        if (t < 196) {
            Ksf[t] = make_float4(bf2f(kreg.x & 0xffff), bf2f_hi(kreg.x),
                                 bf2f(kreg.y & 0xffff), bf2f_hi(kreg.y));
        }
        if (t < 169) Rs[t] = rreg;
        __syncthreads();                          // (A) staging visible

        // ---- prefetch head h+1
        if (h < 7) {
            const ushort* vb = Vb + (size_t)b * V_PER_B + (h + 1) * (HD_ * WD * HDIM);
            const ushort* kb = Kb + (size_t)b * QK_PER_B + (h + 1) * (HD_ * WD * LR);
#pragma unroll
            for (int it = 0; it < 4; ++it) {
                int idx = t + it * 256;
                if (idx < 784) {
                    int pos = idx >> 2, oct = idx & 3;
                    int r = pos / 14, c = pos % 14;
                    vreg[it] = *(const uint4*)&vb[(rs + r) * (WD * HDIM) + (cs + c) * HDIM + oct * 8];
                }
            }
            if (t < 196) {
                int r = t / 14, c = t % 14;
                kreg = *(const uint2*)&kb[(rs + r) * (WD * LR) + (cs + c) * LR];
            }
            if (t < 169) rreg = rpb[(h + 1) * 169 + t];
            qnext = *(const uint2*)&Qb[(size_t)b * QK_PER_B + (h + 1) * (HD_ * WD * LR) + i * (WD * LR) + j * LR];
        }

        // ---- scores: lane p handles kh rows {p, p+4}
        float qx = bf2f(qcur.x & 0xffff) * scale, qy = bf2f_hi(qcur.x) * scale;
        float qz = bf2f(qcur.y & 0xffff) * scale, qw = bf2f_hi(qcur.y) * scale;
        float sum = 0.f;
#pragma unroll
        for (int half = 0; half < 2; ++half) {
            int kh = p + (half << 2);
            if (kh < 7) {
                int kpos  = (oh + kh) * 14 + ow;
                int rbase = rb0 + kh * 13;
                ushort* prow = &Pl[q * 232 + kpos];
#pragma unroll
                for (int kw = 0; kw < 7; ++kw) {
                    float4 kf = Ksf[kpos + kw];
                    float d = Rs[rbase + kw];
                    d = fmaf(qx, kf.x, d);
                    d = fmaf(qy, kf.y, d);
                    d = fmaf(qz, kf.z, d);
                    d = fmaf(qw, kf.w, d);
                    float e = __expf(d);
                    sum += e;
                    prow[kw] = f2bf(e);
                }
            }
        }
        sum += __shfl_xor(sum, 1);
        sum += __shfl_xor(sum, 2);
        if (p == 0) invS[q] = 1.0f / sum;
        __syncthreads();                          // (B) P + invS visible

        // ---- PV MFMA: wave w -> queries w*16..w*16+15
        floatx4 acc0 = {0.f, 0.f, 0.f, 0.f}, acc1 = {0.f, 0.f, 0.f, 0.f};
        const ushort* arow = &Pl[(w * 16 + col) * 232];
        const ushort* b0p  = &Vt[col * 232];
        const ushort* b1p  = &Vt[(col + 16) * 232];
#pragma unroll
        for (int s = 0; s < 7; ++s) {
            int ko = s * 32 + quad * 8;
            short8 a  = *(const short8*)(arow + ko);
            short8 f0 = *(const short8*)(b0p + ko);
            short8 f1 = *(const short8*)(b1p + ko);
            acc0 = __builtin_amdgcn_mfma_f32_16x16x32_bf16(a, f0, acc0, 0, 0, 0);
            acc1 = __builtin_amdgcn_mfma_f32_16x16x32_bf16(a, f1, acc1, 0, 0, 0);
        }

        // ---- epilogue -> Olds (channel block h*32)
#pragma unroll
        for (int rg = 0; rg < 4; ++rg) {
            int qq = w * 16 + quad * 4 + rg;
            float iv = invS[qq];
            Olds[qq * 264 + h * 32 + col]      = f2bf(acc0[rg] * iv);
            Olds[qq * 264 + h * 32 + col + 16] = f2bf(acc1[rg] * iv);
        }
        qcur = qnext;
        __syncthreads();                          // (C) PV/epilogue done
    }

    // ---- out projection: O[64][256] (Olds) @ WpT -> out rows of this tile
    const int lx = lane & 7, ly = lane >> 3;
    const int koff = (lx ^ ly) << 3;
    const int swz = (col & 7) << 4;
    char* Bc = (char*)Bsg;
    floatx4 acc[4][4] = {};

    for (int k0 = 0; k0 < 256; k0 += 64) {
        __syncthreads();
#pragma unroll
        for (int l = 0; l < 8; ++l) {
            int c = (w << 3) + l;                 // 32 chunks of 8 rows
            int row = (c << 3) + ly;
            glds16(&WpT[row * 256 + k0 + koff], &Bsg[c << 9]);
        }
        __syncthreads();
#pragma unroll
        for (int kk = 0; kk < 2; ++kk) {
            const int kx = ((kk << 6) + (quad << 4)) ^ swz;
            short8 bf[4];
#pragma unroll
            for (int nt = 0; nt < 4; ++nt)
                bf[nt] = *(short8*)(Bc + ((w << 6) + (nt << 4) + col) * 128 + kx);
#pragma unroll
            for (int mt = 0; mt < 4; ++mt) {
                short8 a = *(const short8*)&Olds[((mt << 4) + col) * 264 + k0 + (kk << 5) + (quad << 3)];
#pragma unroll
                for (int nt = 0; nt < 4; ++nt)
                    acc[mt][nt] = __builtin_amdgcn_mfma_f32_16x16x32_bf16(a, bf[nt], acc[mt][nt], 0, 0, 0);
            }
        }
    }

#pragma unroll
    for (int mt = 0; mt < 4; ++mt) {
#pragma unroll
        for (int rg = 0; rg < 4; ++rg) {
            int qq = (mt << 4) + (quad << 2) + rg;
            int ii = i0 + (qq >> 3), jj = j0 + (qq & 7);
            float* orow = &out[(((b * HD_ + ii) * WD + jj)) * CD];
#pragma unroll
            for (int nt = 0; nt < 4; ++nt) {
                int gn = (w << 6) + (nt << 4) + col;
                orow[gn] = acc[mt][nt][rg] + bp[gn];
            }
        }
    }
}

extern "C" void kernel_launch(void* const* d_in, const int* in_sizes, int n_in,
                              void* d_out, int out_size, void* d_ws, size_t ws_size,
                              hipStream_t stream) {
    const float* x   = (const float*)d_in[0];
    const float* Wq  = (const float*)d_in[1];
    const float* bq  = (const float*)d_in[2];
    const float* Wk  = (const float*)d_in[3];
    const float* bk  = (const float*)d_in[4];
    const float* Wv  = (const float*)d_in[5];
    const float* bv  = (const float*)d_in[6];
    const float* rpb = (const float*)d_in[7];
    const float* Wp  = (const float*)d_in[8];
    const float* bp  = (const float*)d_in[9];
    float* out = (float*)d_out;

    // workspace layout — bf16 intermediates (Ab eliminated); ~14.7 MB
    ushort* WpkT = (ushort*)d_ws;          // 81920
    ushort* WpT  = WpkT + 81920;           // 65536
    ushort* Qb   = WpT + 65536;            // 401408
    ushort* Kb   = Qb + BD * QK_PER_B;     // 401408
    ushort* Vb   = Kb + BD * QK_PER_B;     // 3211264
    ushort* xb   = Vb + BD * V_PER_B;      // 3211264
    float*  pb   = (float*)(xb + 3211264); // 320

    prep_all<<<(549184 + 255) / 256, 256, 0, stream>>>(
        x, Wq, Wk, Wv, bq, bk, bv, Wp, xb, WpkT, WpT, pb);

    mfma_qkv<<<dim3(5, NROWS / 128), 256, 0, stream>>>(xb, WpkT, pb, Qb, Kb, Vb);

    natten_fused<<<dim3(7, 7, BD), 256, 0, stream>>>(Qb, Kb, Vb, rpb, WpT, bp, out);
}

// Round 5
// 112.152 us; speedup vs baseline: 1.1327x; 1.1327x over previous
//
#include <hip/hip_runtime.h>
#include <hip/hip_bf16.h>

// Problem constants (B,H,W,C) = (4,56,56,256), nh=8, K=7, lr=4, hd=32
#define BD 4
#define HD_ 56
#define WD 56
#define CD 256
#define NH 8
#define KW 7
#define LR 4
#define HDIM 32
#define MB (HD_*WD)              // 3136 rows per batch
#define NROWS (BD*MB)            // 12544 total rows
#define QK_PER_B (HD_*WD*32)     // 100352  (q/k per-batch elements)
#define V_PER_B  (HD_*WD*256)    // 802816

typedef short short8 __attribute__((ext_vector_type(8)));   // 8 bf16 (4 VGPRs)
typedef float floatx4 __attribute__((ext_vector_type(4)));  // MFMA C/D

static __device__ inline ushort f2bf(float f) {
    __hip_bfloat16 h = __float2bfloat16(f);
    return *(ushort*)&h;
}
static __device__ inline float bf2f(uint h16) {          // h16 = bf16 in low 16 bits
    union { uint u; float f; } c; c.u = h16 << 16; return c.f;
}
static __device__ inline float bf2f_hi(uint u) {         // bf16 in high 16 bits
    union { uint v; float f; } c; c.v = u & 0xffff0000u; return c.f;
}

// global -> LDS async DMA, 16B per lane. LDS dest is wave-uniform base +
// lane*16 (HW behavior); global src is per-lane.
typedef const __attribute__((address_space(1))) void* gp1_t;
typedef __attribute__((address_space(3))) void* sp3_t;
static __device__ __forceinline__ void glds16(const void* g, void* s) {
    __builtin_amdgcn_global_load_lds((gp1_t)g, (sp3_t)s, 16, 0, 0);
}

// ---------------- prep: x->bf16 + transposed bf16 weights + packed bias -----
__global__ __launch_bounds__(256) void prep_all(
    const float* __restrict__ x,
    const float* __restrict__ Wq, const float* __restrict__ Wk,
    const float* __restrict__ Wv, const float* __restrict__ bq,
    const float* __restrict__ bk, const float* __restrict__ bv,
    const float* __restrict__ Wp,
    ushort* __restrict__ xb, ushort* __restrict__ WpkT,
    ushort* __restrict__ WpT, float* __restrict__ pb)
{
    int idx = blockIdx.x * 256 + threadIdx.x;
    if (idx < 401408) {
        float4 f0 = *(const float4*)&x[idx * 8];
        float4 f1 = *(const float4*)&x[idx * 8 + 4];
        union { ushort h[8]; uint4 u; } p;
        p.h[0] = f2bf(f0.x); p.h[1] = f2bf(f0.y); p.h[2] = f2bf(f0.z); p.h[3] = f2bf(f0.w);
        p.h[4] = f2bf(f1.x); p.h[5] = f2bf(f1.y); p.h[6] = f2bf(f1.z); p.h[7] = f2bf(f1.w);
        *(uint4*)&xb[idx * 8] = p.u;
    } else if (idx < 401408 + 81920) {
        int j = idx - 401408;
        int n = j >> 8, k = j & 255;
        float v;
        if (n < 32)       v = Wq[k * 32 + n];
        else if (n < 64)  v = Wk[k * 32 + (n - 32)];
        else              v = Wv[k * 256 + (n - 64)];
        WpkT[j] = f2bf(v);
    } else if (idx < 401408 + 81920 + 65536) {
        int j = idx - (401408 + 81920);
        int n = j >> 8, k = j & 255;
        WpT[j] = f2bf(Wp[k * 256 + n]);
    } else if (idx < 401408 + 81920 + 65536 + 320) {
        int n = idx - (401408 + 81920 + 65536);
        pb[n] = (n < 32) ? bq[n] : (n < 64) ? bk[n - 32] : bv[n - 64];
    }
}

// ---------------- MFMA GEMM: QKV projection (proven) ------------------------
static __device__ __forceinline__ void gemm_core_128x64(
    const ushort* __restrict__ Ag, const ushort* __restrict__ Bg,
    ushort* As, ushort* Bs, int m0, int n0, int t, floatx4 (&acc)[4][2])
{
    const int lane = t & 63, w = t >> 6;
    const int lx = lane & 7, ly = lane >> 3;
    const int koff = (lx ^ ly) << 3;
    const int col = lane & 15, quad = lane >> 4;
    const int swz = (col & 7) << 4;
    const int wm = w >> 1, wn = w & 1;
    char* Ac = (char*)As;
    char* Bc = (char*)Bs;

    for (int k0 = 0; k0 < 256; k0 += 64) {
        __syncthreads();
#pragma unroll
        for (int l = 0; l < 4; ++l) {
            int c = (w << 2) + l;
            int row = (c << 3) + ly;
            glds16(&Ag[(m0 + row) * 256 + k0 + koff], &As[c << 9]);
        }
#pragma unroll
        for (int l = 0; l < 2; ++l) {
            int c = (w << 1) + l;
            int row = (c << 3) + ly;
            glds16(&Bg[(n0 + row) * 256 + k0 + koff], &Bs[c << 9]);
        }
        __syncthreads();
#pragma unroll
        for (int kk = 0; kk < 2; ++kk) {
            const int kx = ((kk << 6) + (quad << 4)) ^ swz;
            short8 b0 = *(short8*)(Bc + ((wn << 5) + col) * 128 + kx);
            short8 b1 = *(short8*)(Bc + ((wn << 5) + 16 + col) * 128 + kx);
#pragma unroll
            for (int mt = 0; mt < 4; ++mt) {
                short8 a = *(short8*)(Ac + ((wm << 6) + (mt << 4) + col) * 128 + kx);
                acc[mt][0] = __builtin_amdgcn_mfma_f32_16x16x32_bf16(a, b0, acc[mt][0], 0, 0, 0);
                acc[mt][1] = __builtin_amdgcn_mfma_f32_16x16x32_bf16(a, b1, acc[mt][1], 0, 0, 0);
            }
        }
    }
}

__global__ __launch_bounds__(256) void mfma_qkv(
    const ushort* __restrict__ xb, const ushort* __restrict__ Bt,
    const float* __restrict__ pb, ushort* __restrict__ Qb,
    ushort* __restrict__ Kb, ushort* __restrict__ Vb)
{
    __shared__ ushort As[128 * 64];
    __shared__ ushort Bs[64 * 64];
    const int t = threadIdx.x;
    const int m0 = blockIdx.y * 128, n0 = blockIdx.x * 64;

    floatx4 acc[4][2] = {};
    gemm_core_128x64(xb, Bt, As, Bs, m0, n0, t, acc);

    const int lane = t & 63, w = t >> 6;
    const int col = lane & 15, quad = lane >> 4;
    const int wm = w >> 1, wn = w & 1;
#pragma unroll
    for (int mt = 0; mt < 4; ++mt) {
#pragma unroll
        for (int nt = 0; nt < 2; ++nt) {
            int gn = n0 + (wn << 5) + (nt << 4) + col;
            float bias = pb[gn];
#pragma unroll
            for (int rg = 0; rg < 4; ++rg) {
                int m = m0 + (wm << 6) + (mt << 4) + (quad << 2) + rg;
                ushort h = f2bf(acc[mt][nt][rg] + bias);
                if (gn < 32)        Qb[m * 32 + gn] = h;
                else if (gn < 64)   Kb[m * 32 + (gn - 32)] = h;
                else                Vb[m * 256 + (gn - 64)] = h;
            }
        }
    }
}

// ---------------- NATTEN attention v4: 4x8 query tile, occupancy-first ------
// Block = (tj, ti, b*8+h): 32 queries, one head. Support = 10x14 = 140 pos.
// grid (7,14,32) = 3136 blocks (12.25 blocks-of-work/CU); LDS ~24.5 KB ->
// 6 blocks/CU = 24 waves/CU (vs 7.8% occupancy of the fused version).
// PV = dense GEMM O[32q][32ch] = P[32][160] @ Vt[32][160] via 16x16x32 MFMA,
// P zero outside each query's 49-key window.
// Vt scatter is OCT-MAJOR (oct=idx/140, pos=idx%140): concurrently-writing
// lanes have consecutive pos -> 2-way banks (free), vs 8-way of the
// pos-major mapping (the 2.17M SQ_LDS_BANK_CONFLICT seen in round 4).
__global__ __launch_bounds__(256, 6) void natten_attn4(
    const ushort* __restrict__ Qb, const ushort* __restrict__ Kb,
    const ushort* __restrict__ Vb, const float* __restrict__ rpb,
    ushort* __restrict__ Ab)
{
    __shared__ __align__(16) ushort Pl[32 * 168];   // 10752 B  P[q][key]
    __shared__ __align__(16) ushort Vt[32 * 168];   // 10752 B  V^T[ch][key]
    __shared__ float4 Ksf[140];                     // 2240 B
    __shared__ float  Rs[169];                      // 676 B
    __shared__ float  invS[32];                     // 128 B

    const int tj = blockIdx.x, ti = blockIdx.y;
    const int h = blockIdx.z & 7, b = blockIdx.z >> 3;
    const int t = threadIdx.x;
    const int i0 = ti * 4, j0 = tj * 8;
    const int rs = min(max(i0 - 3, 0), HD_ - 10);
    const int cs = min(max(j0 - 3, 0), WD - 14);

    const ushort* kb = Kb + (size_t)b * QK_PER_B + h * (HD_ * WD * LR);
    const ushort* vb = Vb + (size_t)b * V_PER_B + h * (HD_ * WD * HDIM);

    // ---- zero P (window holes + K-pad) and Vt (K-pad)
#pragma unroll
    for (int it = 0; it < 3; ++it) {
        int idx = t + (it << 8);
        if (idx < 672) {
            *(uint4*)&Pl[idx << 3] = make_uint4(0, 0, 0, 0);
            *(uint4*)&Vt[idx << 3] = make_uint4(0, 0, 0, 0);
        }
    }
    __syncthreads();

    // ---- stage K (fp32), rpb, V^T (bf16, oct-major scatter)
    if (t < 140) {
        int r = t / 14, c = t % 14;
        uint2 kr = *(const uint2*)&kb[(rs + r) * (WD * LR) + (cs + c) * LR];
        Ksf[t] = make_float4(bf2f(kr.x & 0xffff), bf2f_hi(kr.x),
                             bf2f(kr.y & 0xffff), bf2f_hi(kr.y));
    }
    if (t < 169) Rs[t] = rpb[h * 169 + t];
#pragma unroll
    for (int it = 0; it < 3; ++it) {
        int idx = t + (it << 8);
        if (idx < 560) {
            int oct = idx / 140, pos = idx % 140;
            int r = pos / 14, c = pos % 14;
            union { uint4 u; ushort hh[8]; } vv;
            vv.u = *(const uint4*)&vb[(rs + r) * (WD * HDIM) + (cs + c) * HDIM + oct * 8];
            ushort* cp = &Vt[(oct * 8) * 168 + pos];
#pragma unroll
            for (int e = 0; e < 8; ++e) cp[e * 168] = vv.hh[e];
        }
    }

    const int q  = t >> 3, p = t & 7;           // 8 lanes per query
    const int qi = q >> 3, qj = q & 7;
    const int i = i0 + qi, j = j0 + qj;
    uint2 qr2 = *(const uint2*)&Qb[(size_t)b * QK_PER_B + h * (HD_ * WD * LR) + i * (WD * LR) + j * LR];
    __syncthreads();

    // ---- scores: lane p handles kh row p (p==7 idle)
    const int sh = min(max(i - 3, 0), HD_ - KW);
    const int sw = min(max(j - 3, 0), WD - KW);
    const int oh = sh - rs, ow = sw - cs;
    const int rb0 = (sh - i + 6) * 13 + (sw - j + 6);
    const float scale = 0.17677669529663687f;
    float qx = bf2f(qr2.x & 0xffff) * scale, qy = bf2f_hi(qr2.x) * scale;
    float qz = bf2f(qr2.y & 0xffff) * scale, qw = bf2f_hi(qr2.y) * scale;

    float sum = 0.f;
    if (p < 7) {
        int kpos  = (oh + p) * 14 + ow;
        int rbase = rb0 + p * 13;
        ushort* prow = &Pl[q * 168 + kpos];
#pragma unroll
        for (int kw = 0; kw < 7; ++kw) {
            float4 kf = Ksf[kpos + kw];
            float d = Rs[rbase + kw];
            d = fmaf(qx, kf.x, d);
            d = fmaf(qy, kf.y, d);
            d = fmaf(qz, kf.z, d);
            d = fmaf(qw, kf.w, d);
            float e = __expf(d);
            sum += e;
            prow[kw] = f2bf(e);
        }
    }
    sum += __shfl_xor(sum, 1);
    sum += __shfl_xor(sum, 2);
    sum += __shfl_xor(sum, 4);
    if (p == 0) invS[q] = 1.0f / sum;
    __syncthreads();

    // ---- PV MFMA: wave (wm,wn) -> queries wm*16..+15, ch wn*16..+15
    const int lane = t & 63, w = t >> 6;
    const int col = lane & 15, quad = lane >> 4;
    const int wm = w & 1, wn = w >> 1;
    floatx4 acc = {0.f, 0.f, 0.f, 0.f};
    const ushort* arow = &Pl[(wm * 16 + col) * 168];
    const ushort* brow = &Vt[(wn * 16 + col) * 168];
#pragma unroll
    for (int s = 0; s < 5; ++s) {               // K = 160 (140 + zero pad)
        int ko = s * 32 + quad * 8;
        short8 a  = *(const short8*)(arow + ko);
        short8 bb = *(const short8*)(brow + ko);
        acc = __builtin_amdgcn_mfma_f32_16x16x32_bf16(a, bb, acc, 0, 0, 0);
    }

    // ---- epilogue: normalize + bf16 store (D: col=n-idx, quad*4+rg=m-idx)
#pragma unroll
    for (int rg = 0; rg < 4; ++rg) {
        int qq = wm * 16 + quad * 4 + rg;
        float iv = invS[qq];
        int ii = i0 + (qq >> 3), jj = j0 + (qq & 7);
        Ab[(((b * HD_ + ii) * WD + jj)) * CD + h * HDIM + wn * 16 + col] = f2bf(acc[rg] * iv);
    }
}

// ---------------- MFMA GEMM: output projection, 64x64 tiles -----------------
// grid (4, 196) = 784 blocks (vs 392 of the 128-row version) for occupancy.
__global__ __launch_bounds__(256) void mfma_out64(
    const ushort* __restrict__ Ag, const ushort* __restrict__ Bt,
    const float* __restrict__ bp, float* __restrict__ out)
{
    __shared__ ushort As[64 * 64];   // 8 KB
    __shared__ ushort Bs[64 * 64];   // 8 KB
    const int t = threadIdx.x;
    const int m0 = blockIdx.y * 64, n0 = blockIdx.x * 64;
    const int lane = t & 63, w = t >> 6;
    const int lx = lane & 7, ly = lane >> 3;
    const int koff = (lx ^ ly) << 3;
    const int col = lane & 15, quad = lane >> 4;
    const int swz = (col & 7) << 4;
    const int wm = w >> 1, wn = w & 1;
    char* Ac = (char*)As;
    char* Bc = (char*)Bs;
    floatx4 acc[2][2] = {};

    for (int k0 = 0; k0 < 256; k0 += 64) {
        __syncthreads();
#pragma unroll
        for (int l = 0; l < 2; ++l) {
            int c = (w << 1) + l;                 // 8 chunks each of A and B
            int row = (c << 3) + ly;
            glds16(&Ag[(m0 + row) * 256 + k0 + koff], &As[c << 9]);
            glds16(&Bt[(n0 + row) * 256 + k0 + koff], &Bs[c << 9]);
        }
        __syncthreads();
#pragma unroll
        for (int kk = 0; kk < 2; ++kk) {
            const int kx = ((kk << 6) + (quad << 4)) ^ swz;
            short8 b0 = *(short8*)(Bc + ((wn << 5) + col) * 128 + kx);
            short8 b1 = *(short8*)(Bc + ((wn << 5) + 16 + col) * 128 + kx);
#pragma unroll
            for (int mt = 0; mt < 2; ++mt) {
                short8 a = *(short8*)(Ac + ((wm << 5) + (mt << 4) + col) * 128 + kx);
                acc[mt][0] = __builtin_amdgcn_mfma_f32_16x16x32_bf16(a, b0, acc[mt][0], 0, 0, 0);
                acc[mt][1] = __builtin_amdgcn_mfma_f32_16x16x32_bf16(a, b1, acc[mt][1], 0, 0, 0);
            }
        }
    }

#pragma unroll
    for (int mt = 0; mt < 2; ++mt) {
#pragma unroll
        for (int nt = 0; nt < 2; ++nt) {
            int gn = n0 + (wn << 5) + (nt << 4) + col;
            float bias = bp[gn];
#pragma unroll
            for (int rg = 0; rg < 4; ++rg) {
                int m = m0 + (wm << 5) + (mt << 4) + (quad << 2) + rg;
                out[m * 256 + gn] = acc[mt][nt][rg] + bias;
            }
        }
    }
}

extern "C" void kernel_launch(void* const* d_in, const int* in_sizes, int n_in,
                              void* d_out, int out_size, void* d_ws, size_t ws_size,
                              hipStream_t stream) {
    const float* x   = (const float*)d_in[0];
    const float* Wq  = (const float*)d_in[1];
    const float* bq  = (const float*)d_in[2];
    const float* Wk  = (const float*)d_in[3];
    const float* bk  = (const float*)d_in[4];
    const float* Wv  = (const float*)d_in[5];
    const float* bv  = (const float*)d_in[6];
    const float* rpb = (const float*)d_in[7];
    const float* Wp  = (const float*)d_in[8];
    const float* bp  = (const float*)d_in[9];
    float* out = (float*)d_out;

    // workspace layout — bf16 intermediates; ~21 MB of 256 MiB ws
    ushort* WpkT = (ushort*)d_ws;          // 81920
    ushort* WpT  = WpkT + 81920;           // 65536
    ushort* Ab   = WpT + 65536;            // 3211264
    ushort* Qb   = Ab + 3211264;           // 401408
    ushort* Kb   = Qb + BD * QK_PER_B;     // 401408
    ushort* Vb   = Kb + BD * QK_PER_B;     // 3211264
    ushort* xb   = Vb + BD * V_PER_B;      // 3211264
    float*  pb   = (float*)(xb + 3211264); // 320

    prep_all<<<(549184 + 255) / 256, 256, 0, stream>>>(
        x, Wq, Wk, Wv, bq, bk, bv, Wp, xb, WpkT, WpT, pb);

    mfma_qkv<<<dim3(5, NROWS / 128), 256, 0, stream>>>(xb, WpkT, pb, Qb, Kb, Vb);

    natten_attn4<<<dim3(7, 14, 32), 256, 0, stream>>>(Qb, Kb, Vb, rpb, Ab);

    mfma_out64<<<dim3(4, 196), 256, 0, stream>>>(Ab, WpT, bp, out);
}